// Round 19
// baseline (100.625 us; speedup 1.0000x reference)
//
#include <hip/hip_runtime.h>
#include <stdint.h>

#define EMBED 384
#define NHEAD 6
#define HSZ   64
#define BATCH 32
#define SEQ   768
#define MROWS (BATCH * SEQ)   // 24576
#define NTILE (SEQ / 64)      // 12

typedef __bf16 bf16x8 __attribute__((ext_vector_type(8)));
typedef float  f32x4  __attribute__((ext_vector_type(4)));

#define GLD16(gp, lp)                                                        \
  __builtin_amdgcn_global_load_lds(                                          \
      (const __attribute__((address_space(1))) void*)(gp),                   \
      (__attribute__((address_space(3))) void*)(lp), 16, 0, 0)

#define QSCALE 0.18033688011112042f   /* 0.125 * log2(e): exp2-domain scores */

__device__ inline unsigned short nbf(float f) {   // native RNE convert
  union { __bf16 b; unsigned short s; } c; c.b = (__bf16)f; return c.s;
}
__device__ inline uint32_t pk2(float a, float b) { // -> v_cvt_pk_bf16_f32
  union { __bf16 b[2]; uint32_t u; } c;
  c.b[0] = (__bf16)a; c.b[1] = (__bf16)b; return c.u;
}

// ---------------- fused fp32 -> bf16 convert: X then Wq|Wk|Wv|Wo ------------
// Grid-stride (G11): 2048 blocks, ~5 float4 units per thread.
__global__ __launch_bounds__(256) void cvtAll(const float* __restrict__ X,
                                              const float* __restrict__ Wq,
                                              const float* __restrict__ Wk,
                                              const float* __restrict__ Wv,
                                              const float* __restrict__ Wo,
                                              unsigned short* __restrict__ dstW,
                                              unsigned short* __restrict__ dstX) {
  const int NX = MROWS * EMBED, NW = EMBED * EMBED;
  const int total = (NX + 4 * NW) / 4;
  for (int u = blockIdx.x * 256 + threadIdx.x; u < total; u += gridDim.x * 256) {
    const int i = u * 4;
    const float* src;
    unsigned short* dst;
    if (i < NX) {
      src = X + i; dst = dstX + i;
    } else {
      int j = i - NX;
      int wsel = j / NW, r = j - wsel * NW;
      src = ((wsel == 0) ? Wq : (wsel == 1) ? Wk : (wsel == 2) ? Wv : Wo) + r;
      dst = dstW + j;
    }
    float4 v = *reinterpret_cast<const float4*>(src);
    uint2 o;
    o.x = pk2(v.x, v.y); o.y = pk2(v.z, v.w);
    *reinterpret_cast<uint2*>(dst) = o;
  }
}

// ---------------- GEMM: C[m,n] = sum_k A[m,k] * B[n,k]  (B stored [N][K]) ----
// R6-proven body. 1D grid, XCD-chunked bijective swizzle + n-fastest decompose.
// MODE 0: NB=9; scatters Q/K bf16 (Q scaled QSCALE); V transposed VT[bh][d][t].
// MODE 1: NB=3; fp32 out + bias.
template <int MODE>
__global__ __launch_bounds__(256) void gemm_bt(
    const unsigned short* __restrict__ Ab,
    const unsigned short* __restrict__ Bw,
    unsigned short* __restrict__ Qb,
    unsigned short* __restrict__ Kb,
    unsigned short* __restrict__ VT,
    float* __restrict__ Co,
    const float* __restrict__ bias) {
  constexpr int NB = (MODE == 0) ? 9 : 3;          // n-blocks per m-panel
  constexpr int NWG = (MROWS / 128) * NB;          // 1728 / 576, both %8==0
  __shared__ __align__(16) short SH[32768];   // 64KB: 2 bufs x (A 16KB + B 16KB)
  const int tid = threadIdx.x;
  const int lane = tid & 63;
  const int w = tid >> 6;
  const int wm = w >> 1, wn = w & 1;
  // XCD-chunked bijective swizzle (m204): XCD x gets work [x*NWG/8,(x+1)*NWG/8)
  const int work = ((int)blockIdx.x % 8) * (NWG / 8) + (int)blockIdx.x / 8;
  const int m0 = (work / NB) * 128, n0 = (work % NB) * 128;
  const int l15 = lane & 15, lg = lane >> 4;
  char* shc = (char*)SH;

  auto stage = [&](int kt, int buf) {
    short* At = SH + buf * 16384;
    short* Bt = At + 8192;
    const int k0 = kt * 64;
#pragma unroll
    for (int j = 0; j < 4; ++j) {
      const int u = j * 256 + tid;
      const int row = u >> 3, un = u & 7;
      const int sw = (un ^ (row & 7)) * 8;
      const int ub = (j * 256 + (tid & ~63)) * 8;
      GLD16(Ab + (size_t)(m0 + row) * EMBED + k0 + sw, At + ub);
      GLD16(Bw + (size_t)(n0 + row) * EMBED + k0 + sw, Bt + ub);
    }
  };

  f32x4 acc[4][4];
#pragma unroll
  for (int i = 0; i < 4; ++i)
#pragma unroll
    for (int j = 0; j < 4; ++j) acc[i][j] = f32x4{0.f, 0.f, 0.f, 0.f};

  stage(0, 0);
  int cur = 0;
#pragma unroll 1
  for (int kt = 0; kt < 6; ++kt) {
    __syncthreads();                        // drains stage(kt) [vmcnt(0) auto]
    if (kt < 5) stage(kt + 1, cur ^ 1);     // next-tile loads fly under MFMA
    const char* Ac = shc + cur * 32768;
    const char* Bc = Ac + 16384;
#pragma unroll
    for (int kc = 0; kc < 2; ++kc) {
      bf16x8 af[4], bfr[4];
#pragma unroll
      for (int mt = 0; mt < 4; ++mt) {
        const int row = wm * 64 + mt * 16 + l15;
        af[mt] = *(const bf16x8*)(Ac + row * 128 + (((kc * 4 + lg) ^ (row & 7)) * 16));
      }
#pragma unroll
      for (int nt = 0; nt < 4; ++nt) {
        const int row = wn * 64 + nt * 16 + l15;
        bfr[nt] = *(const bf16x8*)(Bc + row * 128 + (((kc * 4 + lg) ^ (row & 7)) * 16));
      }
#pragma unroll
      for (int mt = 0; mt < 4; ++mt)
#pragma unroll
        for (int nt = 0; nt < 4; ++nt)
          acc[mt][nt] = __builtin_amdgcn_mfma_f32_16x16x32_bf16(
              af[mt], bfr[nt], acc[mt][nt], 0, 0, 0);
    }
    cur ^= 1;
  }

  if (MODE == 0 && n0 >= 768) {
    // ---- V blocks: transpose via LDS (reuse buf0, 32KB), write VT coalesced --
    const int b = m0 / SEQ, t0 = m0 - b * SEQ;
    __syncthreads();
#pragma unroll
    for (int mt = 0; mt < 4; ++mt)
#pragma unroll
      for (int nt = 0; nt < 4; ++nt)
#pragma unroll
        for (int r = 0; r < 4; ++r) {
          const int tl = wm * 64 + mt * 16 + lg * 4 + r;
          const int nl = wn * 64 + nt * 16 + l15;
          *(unsigned short*)(shc + nl * 256 + (((tl >> 3) ^ (nl & 7)) * 16) +
                             (tl & 7) * 2) = nbf(acc[mt][nt][r]);
        }
    __syncthreads();
#pragma unroll
    for (int j = 0; j < 8; ++j) {
      const int u = j * 256 + tid;
      const int row = u >> 4, un = u & 15;
      int4 vv = *(const int4*)(shc + row * 256 + ((un ^ (row & 7)) * 16));
      const int cg = (n0 - 768) + row;
      const int h = cg >> 6, d = cg & 63;
      *(int4*)(VT + ((size_t)(b * NHEAD + h) * HSZ + d) * SEQ + t0 + un * 8) = vv;
    }
    return;
  }

  // block-uniform scatter bases (128-wide blocks straddle neither 384 nor 768)
  const int whichU = (MODE == 0) ? (n0 / EMBED) : 0;        // 0=Q, 1=K
  const int bU = m0 / SEQ;                                   // batch index
  const int tU = m0 - bU * SEQ;                              // seq base
#pragma unroll
  for (int mt = 0; mt < 4; ++mt) {
#pragma unroll
    for (int nt = 0; nt < 4; ++nt) {
#pragma unroll
      for (int r = 0; r < 4; ++r) {
        const int ml = wm * 64 + mt * 16 + lg * 4 + r;       // m offset in block
        const int n = n0 + wn * 64 + nt * 16 + l15;
        const float v = acc[mt][nt][r];
        if (MODE == 0) {
          const int c = n - whichU * EMBED;
          const int h = c >> 6, d = c & 63;
          const size_t off =
              ((size_t)((bU * NHEAD + h) * SEQ + tU + ml)) * HSZ + d;
          unsigned short* dstp = (whichU == 0) ? Qb : Kb;
          dstp[off] = nbf(whichU == 0 ? v * QSCALE : v);  // exp2-domain Q scale
        } else {
          Co[(size_t)(m0 + ml) * EMBED + n] = v + bias[n];
        }
      }
    }
  }
}

// ---------------- flash attention, causal, TRIPLE q-tiles per block ----------
// grid (8, 96): bh = (by/4)*8+bx (same-bh blocks share an XCD's L2).
// Block trip handles q-tiles {Q0,Q1,Q2}[trip]; one staged K/V tile feeds up
// to 3 tile() calls. 768 blocks = exactly 3/CU (LDS 40KB).
// exp2 softmax + defer-rescale (R18) + TREE-IFIED fmax/srow chains (this
// round's only delta): 4-way partials, all temps die in-loop (no remat risk).
__global__ __launch_bounds__(256, 3) void attn(const unsigned short* __restrict__ Qb,
                                               const unsigned short* __restrict__ Kb,
                                               const unsigned short* __restrict__ VT,
                                               unsigned short* __restrict__ AO) {
  __shared__ __align__(16) short Kt[2][64 * 64];   // [kv][d] swizzled, dbuf
  __shared__ __align__(16) short Vt[2][64 * 64];   // [d][kv] swizzled, dbuf
  __shared__ __align__(16) short Pl[4][16 * 64];   // per-wave P[q][kv] swizzled
  const int tid = threadIdx.x, lane = tid & 63, w = tid >> 6;
  const int l15 = lane & 15, lg = lane >> 4;
  const int trip = blockIdx.y & 3;
  const int bh = (blockIdx.y >> 2) * 8 + blockIdx.x;
  // balanced triples of q-tiles (each Σ(qt+1) = 19 or 20):
  const int q0t = trip;                                            // 0 1 2 3
  const int q1t = (trip == 3) ? 4 : trip + 5;                      // 5 6 7 4
  const int q2t = (trip == 0) ? 11 : (trip == 1) ? 10 : (trip == 2) ? 8 : 9;
  const size_t base = (size_t)bh * SEQ * HSZ;      // Qb/Kb [bh][t][d]
  char* pw = (char*)(&Pl[w][0]);

  bf16x8 qf0[2], qf1[2], qf2[2];
#pragma unroll
  for (int kc = 0; kc < 2; ++kc) {
    qf0[kc] = *(const bf16x8*)(Qb + base + (size_t)(q0t * 64 + w * 16 + l15) * HSZ +
                               kc * 32 + lg * 8);
    qf1[kc] = *(const bf16x8*)(Qb + base + (size_t)(q1t * 64 + w * 16 + l15) * HSZ +
                               kc * 32 + lg * 8);
    qf2[kc] = *(const bf16x8*)(Qb + base + (size_t)(q2t * 64 + w * 16 + l15) * HSZ +
                               kc * 32 + lg * 8);
  }

  f32x4 o0[4], o1[4], o2[4];
  float m0s = -3.0e38f, l0s = 0.f, m1s = -3.0e38f, l1s = 0.f;
  float m2s = -3.0e38f, l2s = 0.f;
#pragma unroll
  for (int nt = 0; nt < 4; ++nt) {
    o0[nt] = f32x4{0.f, 0.f, 0.f, 0.f};
    o1[nt] = f32x4{0.f, 0.f, 0.f, 0.f};
    o2[nt] = f32x4{0.f, 0.f, 0.f, 0.f};
  }

  auto stage = [&](int kt, int buf) {
#pragma unroll
    for (int j = 0; j < 2; ++j) {
      const int u = j * 256 + tid;
      const int row = u >> 3, un = u & 7;
      const int sw = (un ^ (row & 7)) * 8;
      const int ub = (j * 256 + (tid & ~63)) * 8;
      GLD16(Kb + base + (size_t)(kt * 64 + row) * HSZ + sw, &Kt[buf][ub]);
      GLD16(VT + base + (size_t)row * SEQ + kt * 64 + sw, &Vt[buf][ub]);
    }
  };

  // tile: S^T = mfma(K,Q); lane owns q=l15; exp2 softmax + defer-rescale
  auto tile = [&](const bf16x8* qf, const bf16x8 kf[2][4], const char* Vc,
                  f32x4* o, float& m, float& l, bool diag) {
    f32x4 s[4];
#pragma unroll
    for (int nt = 0; nt < 4; ++nt) s[nt] = f32x4{0.f, 0.f, 0.f, 0.f};
    __builtin_amdgcn_s_setprio(1);
#pragma unroll
    for (int kc = 0; kc < 2; ++kc)
#pragma unroll
      for (int nt = 0; nt < 4; ++nt)
        s[nt] = __builtin_amdgcn_mfma_f32_16x16x32_bf16(kf[kc][nt], qf[kc], s[nt],
                                                        0, 0, 0);
    __builtin_amdgcn_s_setprio(0);
    if (diag) {
#pragma unroll
      for (int nt = 0; nt < 4; ++nt)
#pragma unroll
        for (int r = 0; r < 4; ++r)
          if (nt * 16 + lg * 4 + r > w * 16 + l15) s[nt][r] = -3.0e38f;
    }
    // 4-way fmax tree (temps die here)
    {
      float t0 = fmaxf(fmaxf(s[0][0], s[0][1]), fmaxf(s[0][2], s[0][3]));
      float t1 = fmaxf(fmaxf(s[1][0], s[1][1]), fmaxf(s[1][2], s[1][3]));
      float t2 = fmaxf(fmaxf(s[2][0], s[2][1]), fmaxf(s[2][2], s[2][3]));
      float t3 = fmaxf(fmaxf(s[3][0], s[3][1]), fmaxf(s[3][2], s[3][3]));
      float mx = fmaxf(fmaxf(t0, t1), fmaxf(t2, t3));
      mx = fmaxf(mx, __shfl_xor(mx, 16, 64));
      mx = fmaxf(mx, __shfl_xor(mx, 32, 64));
      // defer-rescale (T13, THR=8 in log2 domain): P bounded by 2^8
      if (!__all(mx <= m + 8.f)) {
        const float mn = fmaxf(m, mx);
        const float alpha = __builtin_amdgcn_exp2f(m - mn);
        m = mn;
        l *= alpha;
#pragma unroll
        for (int nt = 0; nt < 4; ++nt) o[nt] *= alpha;
      }
    }
    // exp + 4-way partial-sum tree (breaks the 16-deep serial add chain)
    {
      float p0 = 0.f, p1 = 0.f, p2 = 0.f, p3 = 0.f;
#pragma unroll
      for (int nt = 0; nt < 4; ++nt) {
        const float e0 = __builtin_amdgcn_exp2f(s[nt][0] - m);
        const float e1 = __builtin_amdgcn_exp2f(s[nt][1] - m);
        const float e2 = __builtin_amdgcn_exp2f(s[nt][2] - m);
        const float e3 = __builtin_amdgcn_exp2f(s[nt][3] - m);
        s[nt][0] = e0; s[nt][1] = e1; s[nt][2] = e2; s[nt][3] = e3;
        p0 += e0; p1 += e1; p2 += e2; p3 += e3;
      }
      float srow = (p0 + p1) + (p2 + p3);
      srow += __shfl_xor(srow, 16, 64);
      srow += __shfl_xor(srow, 32, 64);
      l = l + srow;
    }
#pragma unroll
    for (int nt = 0; nt < 4; ++nt) {
      const int kv = nt * 16 + lg * 4;
      int2 pv;
      pv.x = (int)pk2(s[nt][0], s[nt][1]);
      pv.y = (int)pk2(s[nt][2], s[nt][3]);
      *(int2*)(pw + l15 * 128 + (((kv >> 3) ^ (l15 & 7)) * 16) + (kv & 7) * 2) = pv;
    }
    asm volatile("" ::: "memory");
    bf16x8 pf[2];
#pragma unroll
    for (int kc = 0; kc < 2; ++kc)
      pf[kc] = *(const bf16x8*)(pw + l15 * 128 + (((kc * 4 + lg) ^ (l15 & 7)) * 16));
    __builtin_amdgcn_s_setprio(1);
#pragma unroll
    for (int kc = 0; kc < 2; ++kc)
#pragma unroll
      for (int nt = 0; nt < 4; ++nt) {
        const int row = nt * 16 + l15;
        bf16x8 vf = *(const bf16x8*)(Vc + row * 128 +
                                     (((kc * 4 + lg) ^ (row & 7)) * 16));
        o[nt] = __builtin_amdgcn_mfma_f32_16x16x32_bf16(vf, pf[kc], o[nt], 0, 0, 0);
      }
    __builtin_amdgcn_s_setprio(0);
  };

  stage(0, 0);
  int cur = 0;
#pragma unroll 1
  for (int kt = 0; kt <= q2t; ++kt) {
    __syncthreads();                        // buf[cur] staged; buf[cur^1] free
    if (kt < q2t) stage(kt + 1, cur ^ 1);   // loads fly under compute
    const char* Kc = (const char*)Kt[cur];
    const char* Vc = (const char*)Vt[cur];
    bf16x8 kf[2][4];
#pragma unroll
    for (int kc = 0; kc < 2; ++kc)
#pragma unroll
      for (int nt = 0; nt < 4; ++nt) {
        const int row = nt * 16 + l15;
        kf[kc][nt] = *(const bf16x8*)(Kc + row * 128 +
                                      (((kc * 4 + lg) ^ (row & 7)) * 16));
      }
    tile(qf2, kf, Vc, o2, m2s, l2s, kt == q2t);
    if (kt <= q1t) tile(qf1, kf, Vc, o1, m1s, l1s, kt == q1t);
    if (kt <= q0t) tile(qf0, kf, Vc, o0, m0s, l0s, kt == q0t);
    cur ^= 1;
  }

  // epilogue: lane holds O[q=l15][d=nt*16+lg*4+r]; ushort4 stores x3
  const int bq = bh / NHEAD, h = bh - bq * NHEAD;
  const float inv0 = 1.f / l0s, inv1 = 1.f / l1s, inv2 = 1.f / l2s;
#pragma unroll
  for (int nt = 0; nt < 4; ++nt) {
    ushort4 s0, s1, s2;
    s0.x = nbf(o0[nt][0] * inv0); s0.y = nbf(o0[nt][1] * inv0);
    s0.z = nbf(o0[nt][2] * inv0); s0.w = nbf(o0[nt][3] * inv0);
    s1.x = nbf(o1[nt][0] * inv1); s1.y = nbf(o1[nt][1] * inv1);
    s1.z = nbf(o1[nt][2] * inv1); s1.w = nbf(o1[nt][3] * inv1);
    s2.x = nbf(o2[nt][0] * inv2); s2.y = nbf(o2[nt][1] * inv2);
    s2.z = nbf(o2[nt][2] * inv2); s2.w = nbf(o2[nt][3] * inv2);
    const int col = h * HSZ + nt * 16 + lg * 4;
    *(ushort4*)(AO + ((size_t)(bq * SEQ + q0t * 64 + w * 16 + l15)) * EMBED + col) = s0;
    *(ushort4*)(AO + ((size_t)(bq * SEQ + q1t * 64 + w * 16 + l15)) * EMBED + col) = s1;
    *(ushort4*)(AO + ((size_t)(bq * SEQ + q2t * 64 + w * 16 + l15)) * EMBED + col) = s2;
  }
}

extern "C" void kernel_launch(void* const* d_in, const int* in_sizes, int n_in,
                              void* d_out, int out_size, void* d_ws, size_t ws_size,
                              hipStream_t stream) {
  const float* X  = (const float*)d_in[0];
  const float* Wq = (const float*)d_in[1];
  const float* Wk = (const float*)d_in[2];
  const float* Wv = (const float*)d_in[3];
  const float* Wo = (const float*)d_in[4];
  const float* bo = (const float*)d_in[5];
  float* out = (float*)d_out;

  const size_t NW = (size_t)EMBED * EMBED;   // 147456
  const size_t NX = (size_t)MROWS * EMBED;   // 9437184
  unsigned short* ws    = (unsigned short*)d_ws;
  unsigned short* Wqkvb = ws;                // 3*NW
  unsigned short* Wob   = Wqkvb + 3 * NW;    // NW (contiguous after Wqkvb)
  unsigned short* XbAO  = Wob + NW;          // NX: Xb (pre-attn) then AO
  unsigned short* Qb    = XbAO + NX;         // NX  [B,H,T,D]
  unsigned short* Kb    = Qb + NX;           // NX  [B,H,T,D]
  unsigned short* VTb   = Kb + NX;           // NX  [B,H,D,T] (transposed V)
  // total: 4*NW + 4*NX ushorts = 76.7 MB of d_ws

  cvtAll<<<2048, 256, 0, stream>>>(X, Wq, Wk, Wv, Wo, Wqkvb, XbAO);

  gemm_bt<0><<<(MROWS / 128) * 9, 256, 0, stream>>>(
      XbAO, Wqkvb, Qb, Kb, VTb, nullptr, nullptr);

  attn<<<dim3(8, 96), 256, 0, stream>>>(Qb, Kb, VTb, XbAO);

  gemm_bt<1><<<(MROWS / 128) * 3, 256, 0, stream>>>(
      XbAO, Wob, nullptr, nullptr, nullptr, out, bo);
}

// Round 20
// 99.290 us; speedup vs baseline: 1.0134x; 1.0134x over previous
//
#include <hip/hip_runtime.h>
#include <stdint.h>

#define EMBED 384
#define NHEAD 6
#define HSZ   64
#define BATCH 32
#define SEQ   768
#define MROWS (BATCH * SEQ)   // 24576
#define NTILE (SEQ / 64)      // 12

typedef __bf16 bf16x8 __attribute__((ext_vector_type(8)));
typedef float  f32x4  __attribute__((ext_vector_type(4)));

#define GLD16(gp, lp)                                                        \
  __builtin_amdgcn_global_load_lds(                                          \
      (const __attribute__((address_space(1))) void*)(gp),                   \
      (__attribute__((address_space(3))) void*)(lp), 16, 0, 0)

#define QSCALE 0.18033688011112042f   /* 0.125 * log2(e): exp2-domain scores */

__device__ inline unsigned short nbf(float f) {   // native RNE convert
  union { __bf16 b; unsigned short s; } c; c.b = (__bf16)f; return c.s;
}
__device__ inline uint32_t pk2(float a, float b) { // -> v_cvt_pk_bf16_f32
  union { __bf16 b[2]; uint32_t u; } c;
  c.b[0] = (__bf16)a; c.b[1] = (__bf16)b; return c.u;
}

// ---------------- fused fp32 -> bf16 convert: X then Wq|Wk|Wv|Wo ------------
// Grid-stride (G11): 2048 blocks, ~5 float4 units per thread.
__global__ __launch_bounds__(256) void cvtAll(const float* __restrict__ X,
                                              const float* __restrict__ Wq,
                                              const float* __restrict__ Wk,
                                              const float* __restrict__ Wv,
                                              const float* __restrict__ Wo,
                                              unsigned short* __restrict__ dstW,
                                              unsigned short* __restrict__ dstX) {
  const int NX = MROWS * EMBED, NW = EMBED * EMBED;
  const int total = (NX + 4 * NW) / 4;
  for (int u = blockIdx.x * 256 + threadIdx.x; u < total; u += gridDim.x * 256) {
    const int i = u * 4;
    const float* src;
    unsigned short* dst;
    if (i < NX) {
      src = X + i; dst = dstX + i;
    } else {
      int j = i - NX;
      int wsel = j / NW, r = j - wsel * NW;
      src = ((wsel == 0) ? Wq : (wsel == 1) ? Wk : (wsel == 2) ? Wv : Wo) + r;
      dst = dstW + j;
    }
    float4 v = *reinterpret_cast<const float4*>(src);
    uint2 o;
    o.x = pk2(v.x, v.y); o.y = pk2(v.z, v.w);
    *reinterpret_cast<uint2*>(dst) = o;
  }
}

// ---------------- GEMM: C[m,n] = sum_k A[m,k] * B[n,k]  (B stored [N][K]) ----
// R6-proven body. 1D grid, XCD-chunked bijective swizzle + n-fastest decompose.
// MODE 0: NB=9; scatters Q/K bf16 (Q scaled QSCALE); V transposed VT[bh][d][t].
// MODE 1: NB=3; fp32 out + bias.
template <int MODE>
__global__ __launch_bounds__(256) void gemm_bt(
    const unsigned short* __restrict__ Ab,
    const unsigned short* __restrict__ Bw,
    unsigned short* __restrict__ Qb,
    unsigned short* __restrict__ Kb,
    unsigned short* __restrict__ VT,
    float* __restrict__ Co,
    const float* __restrict__ bias) {
  constexpr int NB = (MODE == 0) ? 9 : 3;          // n-blocks per m-panel
  constexpr int NWG = (MROWS / 128) * NB;          // 1728 / 576, both %8==0
  __shared__ __align__(16) short SH[32768];   // 64KB: 2 bufs x (A 16KB + B 16KB)
  const int tid = threadIdx.x;
  const int lane = tid & 63;
  const int w = tid >> 6;
  const int wm = w >> 1, wn = w & 1;
  // XCD-chunked bijective swizzle (m204): XCD x gets work [x*NWG/8,(x+1)*NWG/8)
  const int work = ((int)blockIdx.x % 8) * (NWG / 8) + (int)blockIdx.x / 8;
  const int m0 = (work / NB) * 128, n0 = (work % NB) * 128;
  const int l15 = lane & 15, lg = lane >> 4;
  char* shc = (char*)SH;

  auto stage = [&](int kt, int buf) {
    short* At = SH + buf * 16384;
    short* Bt = At + 8192;
    const int k0 = kt * 64;
#pragma unroll
    for (int j = 0; j < 4; ++j) {
      const int u = j * 256 + tid;
      const int row = u >> 3, un = u & 7;
      const int sw = (un ^ (row & 7)) * 8;
      const int ub = (j * 256 + (tid & ~63)) * 8;
      GLD16(Ab + (size_t)(m0 + row) * EMBED + k0 + sw, At + ub);
      GLD16(Bw + (size_t)(n0 + row) * EMBED + k0 + sw, Bt + ub);
    }
  };

  f32x4 acc[4][4];
#pragma unroll
  for (int i = 0; i < 4; ++i)
#pragma unroll
    for (int j = 0; j < 4; ++j) acc[i][j] = f32x4{0.f, 0.f, 0.f, 0.f};

  stage(0, 0);
  int cur = 0;
#pragma unroll 1
  for (int kt = 0; kt < 6; ++kt) {
    __syncthreads();                        // drains stage(kt) [vmcnt(0) auto]
    if (kt < 5) stage(kt + 1, cur ^ 1);     // next-tile loads fly under MFMA
    const char* Ac = shc + cur * 32768;
    const char* Bc = Ac + 16384;
#pragma unroll
    for (int kc = 0; kc < 2; ++kc) {
      bf16x8 af[4], bfr[4];
#pragma unroll
      for (int mt = 0; mt < 4; ++mt) {
        const int row = wm * 64 + mt * 16 + l15;
        af[mt] = *(const bf16x8*)(Ac + row * 128 + (((kc * 4 + lg) ^ (row & 7)) * 16));
      }
#pragma unroll
      for (int nt = 0; nt < 4; ++nt) {
        const int row = wn * 64 + nt * 16 + l15;
        bfr[nt] = *(const bf16x8*)(Bc + row * 128 + (((kc * 4 + lg) ^ (row & 7)) * 16));
      }
#pragma unroll
      for (int mt = 0; mt < 4; ++mt)
#pragma unroll
        for (int nt = 0; nt < 4; ++nt)
          acc[mt][nt] = __builtin_amdgcn_mfma_f32_16x16x32_bf16(
              af[mt], bfr[nt], acc[mt][nt], 0, 0, 0);
    }
    cur ^= 1;
  }

  if (MODE == 0 && n0 >= 768) {
    // ---- V blocks: transpose via LDS (reuse buf0, 32KB), write VT coalesced --
    const int b = m0 / SEQ, t0 = m0 - b * SEQ;
    __syncthreads();
#pragma unroll
    for (int mt = 0; mt < 4; ++mt)
#pragma unroll
      for (int nt = 0; nt < 4; ++nt)
#pragma unroll
        for (int r = 0; r < 4; ++r) {
          const int tl = wm * 64 + mt * 16 + lg * 4 + r;
          const int nl = wn * 64 + nt * 16 + l15;
          *(unsigned short*)(shc + nl * 256 + (((tl >> 3) ^ (nl & 7)) * 16) +
                             (tl & 7) * 2) = nbf(acc[mt][nt][r]);
        }
    __syncthreads();
#pragma unroll
    for (int j = 0; j < 8; ++j) {
      const int u = j * 256 + tid;
      const int row = u >> 4, un = u & 15;
      int4 vv = *(const int4*)(shc + row * 256 + ((un ^ (row & 7)) * 16));
      const int cg = (n0 - 768) + row;
      const int h = cg >> 6, d = cg & 63;
      *(int4*)(VT + ((size_t)(b * NHEAD + h) * HSZ + d) * SEQ + t0 + un * 8) = vv;
    }
    return;
  }

  // block-uniform scatter bases (128-wide blocks straddle neither 384 nor 768)
  const int whichU = (MODE == 0) ? (n0 / EMBED) : 0;        // 0=Q, 1=K
  const int bU = m0 / SEQ;                                   // batch index
  const int tU = m0 - bU * SEQ;                              // seq base
#pragma unroll
  for (int mt = 0; mt < 4; ++mt) {
#pragma unroll
    for (int nt = 0; nt < 4; ++nt) {
#pragma unroll
      for (int r = 0; r < 4; ++r) {
        const int ml = wm * 64 + mt * 16 + lg * 4 + r;       // m offset in block
        const int n = n0 + wn * 64 + nt * 16 + l15;
        const float v = acc[mt][nt][r];
        if (MODE == 0) {
          const int c = n - whichU * EMBED;
          const int h = c >> 6, d = c & 63;
          const size_t off =
              ((size_t)((bU * NHEAD + h) * SEQ + tU + ml)) * HSZ + d;
          unsigned short* dstp = (whichU == 0) ? Qb : Kb;
          dstp[off] = nbf(whichU == 0 ? v * QSCALE : v);  // exp2-domain Q scale
        } else {
          Co[(size_t)(m0 + ml) * EMBED + n] = v + bias[n];
        }
      }
    }
  }
}

// ---------------- flash attention, causal, TRIPLE q-tiles per block ----------
// grid (8, 96): bh = (by/4)*8+bx (same-bh blocks share an XCD's L2).
// Block trip handles q-tiles {Q0,Q1,Q2}[trip]; one staged K/V tile feeds up
// to 3 tile() calls. 768 blocks = exactly 3/CU (LDS 40KB).
// exp2-domain softmax (R17) + defer-rescale THR=8 (T13, R18) — best measured.
__global__ __launch_bounds__(256, 3) void attn(const unsigned short* __restrict__ Qb,
                                               const unsigned short* __restrict__ Kb,
                                               const unsigned short* __restrict__ VT,
                                               unsigned short* __restrict__ AO) {
  __shared__ __align__(16) short Kt[2][64 * 64];   // [kv][d] swizzled, dbuf
  __shared__ __align__(16) short Vt[2][64 * 64];   // [d][kv] swizzled, dbuf
  __shared__ __align__(16) short Pl[4][16 * 64];   // per-wave P[q][kv] swizzled
  const int tid = threadIdx.x, lane = tid & 63, w = tid >> 6;
  const int l15 = lane & 15, lg = lane >> 4;
  const int trip = blockIdx.y & 3;
  const int bh = (blockIdx.y >> 2) * 8 + blockIdx.x;
  // balanced triples of q-tiles (each Σ(qt+1) = 19 or 20):
  const int q0t = trip;                                            // 0 1 2 3
  const int q1t = (trip == 3) ? 4 : trip + 5;                      // 5 6 7 4
  const int q2t = (trip == 0) ? 11 : (trip == 1) ? 10 : (trip == 2) ? 8 : 9;
  const size_t base = (size_t)bh * SEQ * HSZ;      // Qb/Kb [bh][t][d]
  char* pw = (char*)(&Pl[w][0]);

  bf16x8 qf0[2], qf1[2], qf2[2];
#pragma unroll
  for (int kc = 0; kc < 2; ++kc) {
    qf0[kc] = *(const bf16x8*)(Qb + base + (size_t)(q0t * 64 + w * 16 + l15) * HSZ +
                               kc * 32 + lg * 8);
    qf1[kc] = *(const bf16x8*)(Qb + base + (size_t)(q1t * 64 + w * 16 + l15) * HSZ +
                               kc * 32 + lg * 8);
    qf2[kc] = *(const bf16x8*)(Qb + base + (size_t)(q2t * 64 + w * 16 + l15) * HSZ +
                               kc * 32 + lg * 8);
  }

  f32x4 o0[4], o1[4], o2[4];
  float m0s = -3.0e38f, l0s = 0.f, m1s = -3.0e38f, l1s = 0.f;
  float m2s = -3.0e38f, l2s = 0.f;
#pragma unroll
  for (int nt = 0; nt < 4; ++nt) {
    o0[nt] = f32x4{0.f, 0.f, 0.f, 0.f};
    o1[nt] = f32x4{0.f, 0.f, 0.f, 0.f};
    o2[nt] = f32x4{0.f, 0.f, 0.f, 0.f};
  }

  auto stage = [&](int kt, int buf) {
#pragma unroll
    for (int j = 0; j < 2; ++j) {
      const int u = j * 256 + tid;
      const int row = u >> 3, un = u & 7;
      const int sw = (un ^ (row & 7)) * 8;
      const int ub = (j * 256 + (tid & ~63)) * 8;
      GLD16(Kb + base + (size_t)(kt * 64 + row) * HSZ + sw, &Kt[buf][ub]);
      GLD16(VT + base + (size_t)row * SEQ + kt * 64 + sw, &Vt[buf][ub]);
    }
  };

  // tile: S^T = mfma(K,Q); lane owns q=l15; exp2 softmax + defer-rescale
  auto tile = [&](const bf16x8* qf, const bf16x8 kf[2][4], const char* Vc,
                  f32x4* o, float& m, float& l, bool diag) {
    f32x4 s[4];
#pragma unroll
    for (int nt = 0; nt < 4; ++nt) s[nt] = f32x4{0.f, 0.f, 0.f, 0.f};
    __builtin_amdgcn_s_setprio(1);
#pragma unroll
    for (int kc = 0; kc < 2; ++kc)
#pragma unroll
      for (int nt = 0; nt < 4; ++nt)
        s[nt] = __builtin_amdgcn_mfma_f32_16x16x32_bf16(kf[kc][nt], qf[kc], s[nt],
                                                        0, 0, 0);
    __builtin_amdgcn_s_setprio(0);
    if (diag) {
#pragma unroll
      for (int nt = 0; nt < 4; ++nt)
#pragma unroll
        for (int r = 0; r < 4; ++r)
          if (nt * 16 + lg * 4 + r > w * 16 + l15) s[nt][r] = -3.0e38f;
    }
    float mx = s[0][0];
#pragma unroll
    for (int nt = 0; nt < 4; ++nt)
#pragma unroll
      for (int r = 0; r < 4; ++r) mx = fmaxf(mx, s[nt][r]);
    mx = fmaxf(mx, __shfl_xor(mx, 16, 64));
    mx = fmaxf(mx, __shfl_xor(mx, 32, 64));
    // defer-rescale (T13, THR=8 in log2 domain): P bounded by 2^8, fine in f32
    if (!__all(mx <= m + 8.f)) {
      const float mn = fmaxf(m, mx);
      const float alpha = __builtin_amdgcn_exp2f(m - mn);
      m = mn;
      l *= alpha;
#pragma unroll
      for (int nt = 0; nt < 4; ++nt) o[nt] *= alpha;
    }
    float srow = 0.f;
#pragma unroll
    for (int nt = 0; nt < 4; ++nt)
#pragma unroll
      for (int r = 0; r < 4; ++r) {
        const float e = __builtin_amdgcn_exp2f(s[nt][r] - m);
        s[nt][r] = e;
        srow += e;
      }
    srow += __shfl_xor(srow, 16, 64);
    srow += __shfl_xor(srow, 32, 64);
    l = l + srow;
#pragma unroll
    for (int nt = 0; nt < 4; ++nt) {
      const int kv = nt * 16 + lg * 4;
      int2 pv;
      pv.x = (int)pk2(s[nt][0], s[nt][1]);
      pv.y = (int)pk2(s[nt][2], s[nt][3]);
      *(int2*)(pw + l15 * 128 + (((kv >> 3) ^ (l15 & 7)) * 16) + (kv & 7) * 2) = pv;
    }
    asm volatile("" ::: "memory");
    bf16x8 pf[2];
#pragma unroll
    for (int kc = 0; kc < 2; ++kc)
      pf[kc] = *(const bf16x8*)(pw + l15 * 128 + (((kc * 4 + lg) ^ (l15 & 7)) * 16));
    __builtin_amdgcn_s_setprio(1);
#pragma unroll
    for (int kc = 0; kc < 2; ++kc)
#pragma unroll
      for (int nt = 0; nt < 4; ++nt) {
        const int row = nt * 16 + l15;
        bf16x8 vf = *(const bf16x8*)(Vc + row * 128 +
                                     (((kc * 4 + lg) ^ (row & 7)) * 16));
        o[nt] = __builtin_amdgcn_mfma_f32_16x16x32_bf16(vf, pf[kc], o[nt], 0, 0, 0);
      }
    __builtin_amdgcn_s_setprio(0);
  };

  stage(0, 0);
  int cur = 0;
#pragma unroll 1
  for (int kt = 0; kt <= q2t; ++kt) {
    __syncthreads();                        // buf[cur] staged; buf[cur^1] free
    if (kt < q2t) stage(kt + 1, cur ^ 1);   // loads fly under compute
    const char* Kc = (const char*)Kt[cur];
    const char* Vc = (const char*)Vt[cur];
    bf16x8 kf[2][4];
#pragma unroll
    for (int kc = 0; kc < 2; ++kc)
#pragma unroll
      for (int nt = 0; nt < 4; ++nt) {
        const int row = nt * 16 + l15;
        kf[kc][nt] = *(const bf16x8*)(Kc + row * 128 +
                                      (((kc * 4 + lg) ^ (row & 7)) * 16));
      }
    tile(qf2, kf, Vc, o2, m2s, l2s, kt == q2t);
    if (kt <= q1t) tile(qf1, kf, Vc, o1, m1s, l1s, kt == q1t);
    if (kt <= q0t) tile(qf0, kf, Vc, o0, m0s, l0s, kt == q0t);
    cur ^= 1;
  }

  // epilogue: lane holds O[q=l15][d=nt*16+lg*4+r]; ushort4 stores x3
  const int bq = bh / NHEAD, h = bh - bq * NHEAD;
  const float inv0 = 1.f / l0s, inv1 = 1.f / l1s, inv2 = 1.f / l2s;
#pragma unroll
  for (int nt = 0; nt < 4; ++nt) {
    ushort4 s0, s1, s2;
    s0.x = nbf(o0[nt][0] * inv0); s0.y = nbf(o0[nt][1] * inv0);
    s0.z = nbf(o0[nt][2] * inv0); s0.w = nbf(o0[nt][3] * inv0);
    s1.x = nbf(o1[nt][0] * inv1); s1.y = nbf(o1[nt][1] * inv1);
    s1.z = nbf(o1[nt][2] * inv1); s1.w = nbf(o1[nt][3] * inv1);
    s2.x = nbf(o2[nt][0] * inv2); s2.y = nbf(o2[nt][1] * inv2);
    s2.z = nbf(o2[nt][2] * inv2); s2.w = nbf(o2[nt][3] * inv2);
    const int col = h * HSZ + nt * 16 + lg * 4;
    *(ushort4*)(AO + ((size_t)(bq * SEQ + q0t * 64 + w * 16 + l15)) * EMBED + col) = s0;
    *(ushort4*)(AO + ((size_t)(bq * SEQ + q1t * 64 + w * 16 + l15)) * EMBED + col) = s1;
    *(ushort4*)(AO + ((size_t)(bq * SEQ + q2t * 64 + w * 16 + l15)) * EMBED + col) = s2;
  }
}

extern "C" void kernel_launch(void* const* d_in, const int* in_sizes, int n_in,
                              void* d_out, int out_size, void* d_ws, size_t ws_size,
                              hipStream_t stream) {
  const float* X  = (const float*)d_in[0];
  const float* Wq = (const float*)d_in[1];
  const float* Wk = (const float*)d_in[2];
  const float* Wv = (const float*)d_in[3];
  const float* Wo = (const float*)d_in[4];
  const float* bo = (const float*)d_in[5];
  float* out = (float*)d_out;

  const size_t NW = (size_t)EMBED * EMBED;   // 147456
  const size_t NX = (size_t)MROWS * EMBED;   // 9437184
  unsigned short* ws    = (unsigned short*)d_ws;
  unsigned short* Wqkvb = ws;                // 3*NW
  unsigned short* Wob   = Wqkvb + 3 * NW;    // NW (contiguous after Wqkvb)
  unsigned short* XbAO  = Wob + NW;          // NX: Xb (pre-attn) then AO
  unsigned short* Qb    = XbAO + NX;         // NX  [B,H,T,D]
  unsigned short* Kb    = Qb + NX;           // NX  [B,H,T,D]
  unsigned short* VTb   = Kb + NX;           // NX  [B,H,D,T] (transposed V)
  // total: 4*NW + 4*NX ushorts = 76.7 MB of d_ws

  cvtAll<<<2048, 256, 0, stream>>>(X, Wq, Wk, Wv, Wo, Wqkvb, XbAO);

  gemm_bt<0><<<(MROWS / 128) * 9, 256, 0, stream>>>(
      XbAO, Wqkvb, Qb, Kb, VTb, nullptr, nullptr);

  attn<<<dim3(8, 96), 256, 0, stream>>>(Qb, Kb, VTb, XbAO);

  gemm_bt<1><<<(MROWS / 128) * 3, 256, 0, stream>>>(
      XbAO, Wob, nullptr, nullptr, nullptr, out, bo);
}